// Round 4
// baseline (1151.316 us; speedup 1.0000x reference)
//
#include <hip/hip_runtime.h>
#include <hip/hip_bf16.h>

#define NUM_U 100000
#define NUM_I 100000
#define NE    1600000
#define NL    100000
#define HDIM  128
#define CAP   48

typedef __attribute__((ext_vector_type(4))) float floatx4;
typedef __attribute__((ext_vector_type(8))) short shortx8;

__device__ __forceinline__ float bf_lo(unsigned v) { return __uint_as_float(v << 16); }
__device__ __forceinline__ float bf_hi(unsigned v) { return __uint_as_float(v & 0xffff0000u); }

__device__ __forceinline__ unsigned pack_bf16x2(float lo, float hi) {
    __hip_bfloat16 l = __float2bfloat16(lo);
    __hip_bfloat16 h = __float2bfloat16(hi);
    unsigned short ul = *(unsigned short*)&l;
    unsigned short uh = *(unsigned short*)&h;
    return (unsigned)ul | ((unsigned)uh << 16);
}

__device__ __forceinline__ int clampi(int x, int hi) {
    return min(max(x, 0), hi - 1);
}

// -------- zero an int array
__global__ void zero_kernel(int* __restrict__ p, int n) {
    int i = blockIdx.x * blockDim.x + threadIdx.x;
    if (i < n) p[i] = 0;
}

// -------- zero f32 tail of d_out beyond NL (poisoned 0xAA otherwise)
__global__ void zero_f32_kernel(float* __restrict__ p, int n) {
    int i = blockIdx.x * blockDim.x + threadIdx.x;
    if (i < n) p[i] = 0.0f;
}

// -------- bucket edges by dst: slot = atomicAdd(deg[dst]); bucket[dst*CAP+slot] = src
__global__ void scatter_kernel(const int* __restrict__ edges, int* __restrict__ deg,
                               int* __restrict__ bucket, int nE) {
    int i = blockIdx.x * blockDim.x + threadIdx.x;
    if (i >= nE) return;
    int s = clampi(edges[i], NUM_U);
    int d = clampi(edges[i + nE], NUM_I);
    int slot = atomicAdd(&deg[d], 1);
    if (slot < CAP) bucket[d * CAP + slot] = s;
}

// -------- per-dst mean aggregation: one wave per dst node, 2 features/lane.
// SRC_F32: x is [N][128] float; else x is [N][64] packed bf16x2. Output packed bf16x2.
template <bool SRC_F32>
__global__ __launch_bounds__(256) void agg_kernel(
    const int* __restrict__ deg, const int* __restrict__ bucket,
    const void* __restrict__ xv, unsigned* __restrict__ mean_out, int n_dst) {
    int wave = (blockIdx.x * blockDim.x + threadIdx.x) >> 6;
    int lane = threadIdx.x & 63;
    if (wave >= n_dst) return;
    int d = deg[wave];
    int cnt = min(d, CAP);
    int srcs = (lane < cnt) ? bucket[wave * CAP + lane] : 0;
    float a0 = 0.f, a1 = 0.f;
    if constexpr (SRC_F32) {
        const float* xf = (const float*)xv;
        int e = 0;
        for (; e + 4 <= cnt; e += 4) {
            int s0 = __shfl(srcs, e);
            int s1 = __shfl(srcs, e + 1);
            int s2 = __shfl(srcs, e + 2);
            int s3 = __shfl(srcs, e + 3);
            float2 v0 = *(const float2*)(xf + (size_t)s0 * 128 + lane * 2);
            float2 v1 = *(const float2*)(xf + (size_t)s1 * 128 + lane * 2);
            float2 v2 = *(const float2*)(xf + (size_t)s2 * 128 + lane * 2);
            float2 v3 = *(const float2*)(xf + (size_t)s3 * 128 + lane * 2);
            a0 += v0.x + v1.x + v2.x + v3.x;
            a1 += v0.y + v1.y + v2.y + v3.y;
        }
        for (; e < cnt; e++) {
            int s0 = __shfl(srcs, e);
            float2 v0 = *(const float2*)(xf + (size_t)s0 * 128 + lane * 2);
            a0 += v0.x; a1 += v0.y;
        }
    } else {
        const unsigned* xb = (const unsigned*)xv;
        int e = 0;
        for (; e + 4 <= cnt; e += 4) {
            int s0 = __shfl(srcs, e);
            int s1 = __shfl(srcs, e + 1);
            int s2 = __shfl(srcs, e + 2);
            int s3 = __shfl(srcs, e + 3);
            unsigned v0 = xb[(size_t)s0 * 64 + lane];
            unsigned v1 = xb[(size_t)s1 * 64 + lane];
            unsigned v2 = xb[(size_t)s2 * 64 + lane];
            unsigned v3 = xb[(size_t)s3 * 64 + lane];
            a0 += bf_lo(v0) + bf_lo(v1) + bf_lo(v2) + bf_lo(v3);
            a1 += bf_hi(v0) + bf_hi(v1) + bf_hi(v2) + bf_hi(v3);
        }
        for (; e < cnt; e++) {
            int s0 = __shfl(srcs, e);
            unsigned v0 = xb[(size_t)s0 * 64 + lane];
            a0 += bf_lo(v0); a1 += bf_hi(v0);
        }
    }
    float scale = 1.0f / (float)max(d, 1);
    mean_out[(size_t)wave * 64 + lane] = pack_bf16x2(a0 * scale, a1 * scale);
}

// -------- transpose the 4 f32 weight pairs into bf16 Bt[which][n][k], k=[w_l rows|w_r rows]
__global__ void transpose_w4_kernel(
    const float* __restrict__ w1l_rates, const float* __restrict__ w1r_rates,
    const float* __restrict__ w1l_rev,   const float* __restrict__ w1r_rev,
    const float* __restrict__ w2l_rates, const float* __restrict__ w2r_rates,
    const float* __restrict__ w2l_rev,   const float* __restrict__ w2r_rev,
    short* __restrict__ Bt) {
    int idx = blockIdx.x * blockDim.x + threadIdx.x;  // 0 .. 4*32768-1
    int which = idx >> 15;
    int r = idx & 32767;
    int n = r >> 8;
    int k = r & 255;
    const float *wl, *wr;
    switch (which) {
        case 0:  wl = w1l_rates; wr = w1r_rates; break;
        case 1:  wl = w1l_rev;   wr = w1r_rev;   break;
        case 2:  wl = w2l_rates; wr = w2r_rates; break;
        default: wl = w2l_rev;   wr = w2r_rev;   break;
    }
    float v = (k < 128) ? wl[k * 128 + n] : wr[(k - 128) * 128 + n];
    __hip_bfloat16 b = __float2bfloat16(v);
    Bt[idx] = *(const short*)&b;
}

// -------- fused: out = relu(normalize(mean @ w_l + b + x_dst @ w_r)), bf16 out
// A = [mean | x_dst] (K=256), B = Bt[n][k], C tile 128x128 per block, 4 waves of 64x64.
// XDST_F32: x_dst is [N][128] float (converted to bf16 during staging); else packed bf16x2.
// Safe with outb aliasing xdstb (bf16 case): each block reads only its own 128 rows and
// staging reads drain at a barrier before any epilogue store.
template <bool XDST_F32>
__global__ __launch_bounds__(256) void sage_fused_kernel(
    const unsigned* __restrict__ meanb,   // [N][64] packed bf16x2
    const void* __restrict__ xdstv,       // [N][128] f32 or [N][64] packed bf16x2
    const short* __restrict__ Bt,         // [128][256] bf16 bits, Bt[n][k]
    const float* __restrict__ bias,       // [128] f32
    unsigned* __restrict__ outb,          // [N][64] packed bf16x2
    int n_rows) {
    __shared__ __align__(16) short A_lds[128 * 72];   // 64-wide k-tile, pad to 72
    __shared__ float rowsum[128][2];

    const int tid  = threadIdx.x;
    const int lane = tid & 63;
    const int wv   = tid >> 6;
    const int wm   = wv >> 1;
    const int wn   = wv & 1;
    const int rb   = blockIdx.x * 128;
    const int l15  = lane & 15;
    const int lq   = lane >> 4;

    floatx4 acc[4][4];
#pragma unroll
    for (int nt = 0; nt < 4; nt++) {
        float b = bias[wn * 64 + nt * 16 + l15];
#pragma unroll
        for (int mt = 0; mt < 4; mt++) acc[mt][nt] = (floatx4){b, b, b, b};
    }

    for (int kt = 0; kt < 4; kt++) {
        __syncthreads();
#pragma unroll
        for (int j = 0; j < 4; j++) {
            int c = tid + j * 256;          // chunk 0..1023, 8 bf16 elems each
            int row = c >> 3;
            int kc = (c & 7) * 8;           // elem offset within 64-wide k-tile
            int grow = rb + row;
            uint4 v = make_uint4(0u, 0u, 0u, 0u);
            if (kt < 2) {
                if (grow < n_rows)
                    v = *(const uint4*)(meanb + (size_t)grow * 64 + (kt & 1) * 32 + (kc >> 1));
            } else if constexpr (XDST_F32) {
                if (grow < n_rows) {
                    const float* xf = (const float*)xdstv + (size_t)grow * 128 + (kt & 1) * 64 + kc;
                    float4 f0 = *(const float4*)xf;
                    float4 f1 = *(const float4*)(xf + 4);
                    v.x = pack_bf16x2(f0.x, f0.y);
                    v.y = pack_bf16x2(f0.z, f0.w);
                    v.z = pack_bf16x2(f1.x, f1.y);
                    v.w = pack_bf16x2(f1.z, f1.w);
                }
            } else {
                if (grow < n_rows)
                    v = *(const uint4*)((const unsigned*)xdstv + (size_t)grow * 64 +
                                        (kt & 1) * 32 + (kc >> 1));
            }
            *(uint4*)&A_lds[row * 72 + kc] = v;
        }
        __syncthreads();

#pragma unroll
        for (int kk = 0; kk < 64; kk += 32) {
            shortx8 af[4], bfr[4];
#pragma unroll
            for (int mt = 0; mt < 4; mt++) {
                int row_l = wm * 64 + mt * 16 + l15;
                af[mt] = *(const shortx8*)&A_lds[row_l * 72 + kk + lq * 8];
            }
#pragma unroll
            for (int nt = 0; nt < 4; nt++) {
                int col = wn * 64 + nt * 16 + l15;
                int kg = kt * 64 + kk + lq * 8;
                bfr[nt] = *(const shortx8*)(Bt + col * 256 + kg);
            }
#pragma unroll
            for (int mt = 0; mt < 4; mt++)
#pragma unroll
                for (int nt = 0; nt < 4; nt++)
                    acc[mt][nt] = __builtin_amdgcn_mfma_f32_16x16x32_bf16(
                        af[mt], bfr[nt], acc[mt][nt], 0, 0, 0);
        }
    }

    // row sums of squares: in-lane over nt, across 16 lanes of a quad-group,
    // then across the two column-half waves via LDS.
#pragma unroll
    for (int mt = 0; mt < 4; mt++) {
#pragma unroll
        for (int r = 0; r < 4; r++) {
            float p = 0.f;
#pragma unroll
            for (int nt = 0; nt < 4; nt++) { float x = acc[mt][nt][r]; p += x * x; }
            for (int o = 1; o < 16; o <<= 1) p += __shfl_xor(p, o);
            if (l15 == 0) rowsum[wm * 64 + mt * 16 + lq * 4 + r][wn] = p;
        }
    }
    __syncthreads();

    // epilogue: normalize, relu, pack to bf16x2. Lane l15 covers cols {nt*16+l15};
    // adjacent-col pairing for packing done via shfl with the neighboring lane.
#pragma unroll
    for (int mt = 0; mt < 4; mt++) {
#pragma unroll
        for (int r = 0; r < 4; r++) {
            int row_l = wm * 64 + mt * 16 + lq * 4 + r;
            int grow = rb + row_l;
            float s = rowsum[row_l][0] + rowsum[row_l][1];
            float inv = 1.f / fmaxf(sqrtf(s), 1e-12f);
#pragma unroll
            for (int nt = 0; nt < 4; nt++) {
                float v = fmaxf(acc[mt][nt][r] * inv, 0.f);
                // lane pairing: lanes (2j, 2j+1) hold cols (nt*16+2j, nt*16+2j+1)
                float vnb = __shfl_xor(v, 1);
                if (grow < n_rows && (l15 & 1) == 0) {
                    int colpair = (wn * 64 + nt * 16 + l15) >> 1;   // uint index
                    outb[(size_t)grow * 64 + colpair] = pack_bf16x2(v, vnb);
                }
            }
        }
    }
}

// -------- classifier: dot(xu2[src], xi2[dst]) per labeled edge, one wave per pair
__global__ __launch_bounds__(256) void classifier_kernel(
    const unsigned* __restrict__ xu, const unsigned* __restrict__ xi,
    const int* __restrict__ eli, float* __restrict__ out, int nL) {
    int wave = (blockIdx.x * blockDim.x + threadIdx.x) >> 6;
    int lane = threadIdx.x & 63;
    if (wave >= nL) return;
    int su = clampi(eli[wave], NUM_U);
    int di = clampi(eli[wave + nL], NUM_I);
    unsigned a = xu[(size_t)su * 64 + lane];
    unsigned b = xi[(size_t)di * 64 + lane];
    float p = bf_lo(a) * bf_lo(b) + bf_hi(a) * bf_hi(b);
    for (int o = 32; o; o >>= 1) p += __shfl_xor(p, o);
    if (lane == 0) out[wave] = p;
}

extern "C" void kernel_launch(void* const* d_in, const int* in_sizes, int n_in,
                              void* d_out, int out_size, void* d_ws, size_t ws_size,
                              hipStream_t stream) {
    const float* emb_user = (const float*)d_in[0];
    const float* emb_item = (const float*)d_in[1];
    const int* edge_rates = (const int*)d_in[2];
    const int* edge_rev   = (const int*)d_in[3];
    const int* eli        = (const int*)d_in[4];
    const float* b1_rates = (const float*)d_in[13];
    const float* b1_rev   = (const float*)d_in[14];
    const float* b2_rates = (const float*)d_in[15];
    const float* b2_rev   = (const float*)d_in[16];

    // workspace layout — total ~122 MiB
    char* p = (char*)d_ws;
    auto alloc = [&](size_t bytes) -> void* {
        void* q = (void*)p;
        p += (bytes + 511) & ~(size_t)511;
        return q;
    };
    int* deg    = (int*)alloc((size_t)NUM_I * 4);                // 0.4 MB (shared)
    int* bucket = (int*)alloc((size_t)NUM_I * CAP * 4);          // 19.2 MB (shared)
    unsigned* meanI = (unsigned*)alloc((size_t)NUM_I * 64 * 4);  // 25.6 MB
    unsigned* meanU = (unsigned*)alloc((size_t)NUM_U * 64 * 4);  // 25.6 MB
    unsigned* xi    = (unsigned*)alloc((size_t)NUM_I * 64 * 4);  // 25.6 MB (xi1 then xi2)
    unsigned* xu    = (unsigned*)alloc((size_t)NUM_U * 64 * 4);  // 25.6 MB (xu1 then xu2)
    short* Bt = (short*)alloc((size_t)4 * 32768 * 2);            // 0.26 MB

    const int zeroBlocks = (NUM_I + 255) / 256;
    const int scatBlocks = (NE + 255) / 256;
    const int aggBlocks  = (NUM_I * 64 + 255) / 256;
    const int gemmBlocks = (NUM_I + 127) / 128;

    if (out_size > NL) {
        int tail = out_size - NL;
        zero_f32_kernel<<<(tail + 255) / 256, 256, 0, stream>>>((float*)d_out + NL, tail);
    }

    transpose_w4_kernel<<<512, 256, 0, stream>>>(
        (const float*)d_in[5], (const float*)d_in[6],
        (const float*)d_in[7], (const float*)d_in[8],
        (const float*)d_in[9], (const float*)d_in[10],
        (const float*)d_in[11], (const float*)d_in[12], Bt);

    // ---- layer 1 aggregations (bucket rebuilt per edge type)
    zero_kernel<<<zeroBlocks, 256, 0, stream>>>(deg, NUM_I);
    scatter_kernel<<<scatBlocks, 256, 0, stream>>>(edge_rates, deg, bucket, NE);
    agg_kernel<true><<<aggBlocks, 256, 0, stream>>>(deg, bucket, emb_user, meanI, NUM_I);

    zero_kernel<<<zeroBlocks, 256, 0, stream>>>(deg, NUM_U);
    scatter_kernel<<<scatBlocks, 256, 0, stream>>>(edge_rev, deg, bucket, NE);
    agg_kernel<true><<<aggBlocks, 256, 0, stream>>>(deg, bucket, emb_item, meanU, NUM_U);

    // ---- layer 1 GEMMs (x_dst = f32 embeddings)
    sage_fused_kernel<true><<<gemmBlocks, 256, 0, stream>>>(meanI, emb_item,
                                                            Bt + 0 * 32768, b1_rates,
                                                            xi, NUM_I);
    sage_fused_kernel<true><<<gemmBlocks, 256, 0, stream>>>(meanU, emb_user,
                                                            Bt + 1 * 32768, b1_rev,
                                                            xu, NUM_U);

    // ---- layer 2 aggregations (both finish before the in-place GEMMs overwrite x1)
    zero_kernel<<<zeroBlocks, 256, 0, stream>>>(deg, NUM_I);
    scatter_kernel<<<scatBlocks, 256, 0, stream>>>(edge_rates, deg, bucket, NE);
    agg_kernel<false><<<aggBlocks, 256, 0, stream>>>(deg, bucket, xu, meanI, NUM_I);

    zero_kernel<<<zeroBlocks, 256, 0, stream>>>(deg, NUM_U);
    scatter_kernel<<<scatBlocks, 256, 0, stream>>>(edge_rev, deg, bucket, NE);
    agg_kernel<false><<<aggBlocks, 256, 0, stream>>>(deg, bucket, xi, meanU, NUM_U);

    // ---- layer 2 GEMMs (in-place over x1 buffers)
    sage_fused_kernel<false><<<gemmBlocks, 256, 0, stream>>>(meanI, xi, Bt + 2 * 32768,
                                                             b2_rates, xi, NUM_I);
    sage_fused_kernel<false><<<gemmBlocks, 256, 0, stream>>>(meanU, xu, Bt + 3 * 32768,
                                                             b2_rev, xu, NUM_U);

    classifier_kernel<<<(NL * 64 + 255) / 256, 256, 0, stream>>>(xu, xi, eli,
                                                                 (float*)d_out, NL);
}

// Round 5
// 826.215 us; speedup vs baseline: 1.3935x; 1.3935x over previous
//
#include <hip/hip_runtime.h>
#include <hip/hip_bf16.h>

#define NUM_U 100000
#define NUM_I 100000
#define NE    1600000
#define NL    100000
#define HDIM  128
#define CAP   48

typedef __attribute__((ext_vector_type(4))) float floatx4;
typedef __attribute__((ext_vector_type(8))) short shortx8;

__device__ __forceinline__ float bf_lo(unsigned v) { return __uint_as_float(v << 16); }
__device__ __forceinline__ float bf_hi(unsigned v) { return __uint_as_float(v & 0xffff0000u); }

__device__ __forceinline__ unsigned pack_bf16x2(float lo, float hi) {
    __hip_bfloat16 l = __float2bfloat16(lo);
    __hip_bfloat16 h = __float2bfloat16(hi);
    unsigned short ul = *(unsigned short*)&l;
    unsigned short uh = *(unsigned short*)&h;
    return (unsigned)ul | ((unsigned)uh << 16);
}

__device__ __forceinline__ int clampi(int x, int hi) {
    return min(max(x, 0), hi - 1);
}

// -------- zero an int array
__global__ void zero_kernel(int* __restrict__ p, int n) {
    int i = blockIdx.x * blockDim.x + threadIdx.x;
    if (i < n) p[i] = 0;
}

// -------- zero f32 tail of d_out beyond NL (poisoned 0xAA otherwise)
__global__ void zero_f32_kernel(float* __restrict__ p, int n) {
    int i = blockIdx.x * blockDim.x + threadIdx.x;
    if (i < n) p[i] = 0.0f;
}

// -------- convert f32 [N][128] -> packed bf16x2 [N][64], coalesced streaming
__global__ void conv_bf16_kernel(const float* __restrict__ in, unsigned* __restrict__ out,
                                 int n_pairs) {
    int i = blockIdx.x * blockDim.x + threadIdx.x;
    if (i >= n_pairs) return;
    float2 v = ((const float2*)in)[i];
    out[i] = pack_bf16x2(v.x, v.y);
}

// -------- bucket edges by dst: slot = atomicAdd(deg[dst]); bucket[dst*CAP+slot] = src
__global__ void scatter_kernel(const int* __restrict__ edges, int* __restrict__ deg,
                               int* __restrict__ bucket, int nE) {
    int i = blockIdx.x * blockDim.x + threadIdx.x;
    if (i >= nE) return;
    int s = clampi(edges[i], NUM_U);
    int d = clampi(edges[i + nE], NUM_I);
    int slot = atomicAdd(&deg[d], 1);
    if (slot < CAP) bucket[d * CAP + slot] = s;
}

// -------- per-dst mean aggregation: one wave per dst node, 2 features/lane.
// x: [N][64] packed bf16x2. Output packed bf16x2.
__global__ __launch_bounds__(256) void agg_kernel(
    const int* __restrict__ deg, const int* __restrict__ bucket,
    const unsigned* __restrict__ xb, unsigned* __restrict__ mean_out, int n_dst) {
    int wave = (blockIdx.x * blockDim.x + threadIdx.x) >> 6;
    int lane = threadIdx.x & 63;
    if (wave >= n_dst) return;
    int d = deg[wave];
    int cnt = min(d, CAP);
    int srcs = (lane < cnt) ? bucket[wave * CAP + lane] : 0;
    float a0 = 0.f, a1 = 0.f;
    int e = 0;
    for (; e + 4 <= cnt; e += 4) {
        int s0 = __shfl(srcs, e);
        int s1 = __shfl(srcs, e + 1);
        int s2 = __shfl(srcs, e + 2);
        int s3 = __shfl(srcs, e + 3);
        unsigned v0 = xb[(size_t)s0 * 64 + lane];
        unsigned v1 = xb[(size_t)s1 * 64 + lane];
        unsigned v2 = xb[(size_t)s2 * 64 + lane];
        unsigned v3 = xb[(size_t)s3 * 64 + lane];
        a0 += bf_lo(v0) + bf_lo(v1) + bf_lo(v2) + bf_lo(v3);
        a1 += bf_hi(v0) + bf_hi(v1) + bf_hi(v2) + bf_hi(v3);
    }
    for (; e < cnt; e++) {
        int s0 = __shfl(srcs, e);
        unsigned v0 = xb[(size_t)s0 * 64 + lane];
        a0 += bf_lo(v0); a1 += bf_hi(v0);
    }
    float scale = 1.0f / (float)max(d, 1);
    mean_out[(size_t)wave * 64 + lane] = pack_bf16x2(a0 * scale, a1 * scale);
}

// -------- transpose the 4 f32 weight pairs into bf16 Bt[which][n][k], k=[w_l rows|w_r rows]
__global__ void transpose_w4_kernel(
    const float* __restrict__ w1l_rates, const float* __restrict__ w1r_rates,
    const float* __restrict__ w1l_rev,   const float* __restrict__ w1r_rev,
    const float* __restrict__ w2l_rates, const float* __restrict__ w2r_rates,
    const float* __restrict__ w2l_rev,   const float* __restrict__ w2r_rev,
    short* __restrict__ Bt) {
    int idx = blockIdx.x * blockDim.x + threadIdx.x;  // 0 .. 4*32768-1
    int which = idx >> 15;
    int r = idx & 32767;
    int n = r >> 8;
    int k = r & 255;
    const float *wl, *wr;
    switch (which) {
        case 0:  wl = w1l_rates; wr = w1r_rates; break;
        case 1:  wl = w1l_rev;   wr = w1r_rev;   break;
        case 2:  wl = w2l_rates; wr = w2r_rates; break;
        default: wl = w2l_rev;   wr = w2r_rev;   break;
    }
    float v = (k < 128) ? wl[k * 128 + n] : wr[(k - 128) * 128 + n];
    __hip_bfloat16 b = __float2bfloat16(v);
    Bt[idx] = *(const short*)&b;
}

// -------- fused: out = relu(normalize(mean @ w_l + b + x_dst @ w_r)), bf16 out
// A = [mean | x_dst] (K=256), B = Bt[n][k], C tile 128x128 per block, 4 waves of 64x64.
// Safe with outb aliasing xdstb: each block reads only its own 128 rows of xdstb and
// all staging reads drain at a barrier before any epilogue store.
__global__ __launch_bounds__(256) void sage_fused_kernel(
    const unsigned* __restrict__ meanb,   // [N][64] packed bf16x2
    const unsigned* __restrict__ xdstb,   // [N][64] packed bf16x2
    const short* __restrict__ Bt,         // [128][256] bf16 bits, Bt[n][k]
    const float* __restrict__ bias,       // [128] f32
    unsigned* __restrict__ outb,          // [N][64] packed bf16x2
    int n_rows) {
    __shared__ __align__(16) short A_lds[128 * 72];   // 64-wide k-tile, pad to 72
    __shared__ float rowsum[128][2];

    const int tid  = threadIdx.x;
    const int lane = tid & 63;
    const int wv   = tid >> 6;
    const int wm   = wv >> 1;
    const int wn   = wv & 1;
    const int rb   = blockIdx.x * 128;
    const int l15  = lane & 15;
    const int lq   = lane >> 4;

    floatx4 acc[4][4];
#pragma unroll
    for (int nt = 0; nt < 4; nt++) {
        float b = bias[wn * 64 + nt * 16 + l15];
#pragma unroll
        for (int mt = 0; mt < 4; mt++) acc[mt][nt] = (floatx4){b, b, b, b};
    }

    for (int kt = 0; kt < 4; kt++) {
        __syncthreads();
        const unsigned* srcbuf = (kt < 2) ? meanb : xdstb;
        const int kbase_u = (kt & 1) * 32;  // uint offset within the 128-elem row
#pragma unroll
        for (int j = 0; j < 4; j++) {
            int c = tid + j * 256;          // chunk 0..1023, 8 bf16 elems each
            int row = c >> 3;
            int kc = (c & 7) * 8;           // elem offset within 64-wide k-tile
            int grow = rb + row;
            uint4 v = make_uint4(0u, 0u, 0u, 0u);
            if (grow < n_rows)
                v = *(const uint4*)(srcbuf + (size_t)grow * 64 + kbase_u + (kc >> 1));
            *(uint4*)&A_lds[row * 72 + kc] = v;
        }
        __syncthreads();

#pragma unroll
        for (int kk = 0; kk < 64; kk += 32) {
            shortx8 af[4], bfr[4];
#pragma unroll
            for (int mt = 0; mt < 4; mt++) {
                int row_l = wm * 64 + mt * 16 + l15;
                af[mt] = *(const shortx8*)&A_lds[row_l * 72 + kk + lq * 8];
            }
#pragma unroll
            for (int nt = 0; nt < 4; nt++) {
                int col = wn * 64 + nt * 16 + l15;
                int kg = kt * 64 + kk + lq * 8;
                bfr[nt] = *(const shortx8*)(Bt + col * 256 + kg);
            }
#pragma unroll
            for (int mt = 0; mt < 4; mt++)
#pragma unroll
                for (int nt = 0; nt < 4; nt++)
                    acc[mt][nt] = __builtin_amdgcn_mfma_f32_16x16x32_bf16(
                        af[mt], bfr[nt], acc[mt][nt], 0, 0, 0);
        }
    }

    // row sums of squares: in-lane over nt, across 16 lanes of a quad-group,
    // then across the two column-half waves via LDS.
#pragma unroll
    for (int mt = 0; mt < 4; mt++) {
#pragma unroll
        for (int r = 0; r < 4; r++) {
            float p = 0.f;
#pragma unroll
            for (int nt = 0; nt < 4; nt++) { float x = acc[mt][nt][r]; p += x * x; }
            for (int o = 1; o < 16; o <<= 1) p += __shfl_xor(p, o);
            if (l15 == 0) rowsum[wm * 64 + mt * 16 + lq * 4 + r][wn] = p;
        }
    }
    __syncthreads();

    // epilogue: normalize, relu, pack to bf16x2 (adjacent-col pairing via shfl).
#pragma unroll
    for (int mt = 0; mt < 4; mt++) {
#pragma unroll
        for (int r = 0; r < 4; r++) {
            int row_l = wm * 64 + mt * 16 + lq * 4 + r;
            int grow = rb + row_l;
            float s = rowsum[row_l][0] + rowsum[row_l][1];
            float inv = 1.f / fmaxf(sqrtf(s), 1e-12f);
#pragma unroll
            for (int nt = 0; nt < 4; nt++) {
                float v = fmaxf(acc[mt][nt][r] * inv, 0.f);
                float vnb = __shfl_xor(v, 1);
                if (grow < n_rows && (l15 & 1) == 0) {
                    int colpair = (wn * 64 + nt * 16 + l15) >> 1;   // uint index
                    outb[(size_t)grow * 64 + colpair] = pack_bf16x2(v, vnb);
                }
            }
        }
    }
}

// -------- classifier: dot(xu2[src], xi2[dst]) per labeled edge, one wave per pair
__global__ __launch_bounds__(256) void classifier_kernel(
    const unsigned* __restrict__ xu, const unsigned* __restrict__ xi,
    const int* __restrict__ eli, float* __restrict__ out, int nL) {
    int wave = (blockIdx.x * blockDim.x + threadIdx.x) >> 6;
    int lane = threadIdx.x & 63;
    if (wave >= nL) return;
    int su = clampi(eli[wave], NUM_U);
    int di = clampi(eli[wave + nL], NUM_I);
    unsigned a = xu[(size_t)su * 64 + lane];
    unsigned b = xi[(size_t)di * 64 + lane];
    float p = bf_lo(a) * bf_lo(b) + bf_hi(a) * bf_hi(b);
    for (int o = 32; o; o >>= 1) p += __shfl_xor(p, o);
    if (lane == 0) out[wave] = p;
}

extern "C" void kernel_launch(void* const* d_in, const int* in_sizes, int n_in,
                              void* d_out, int out_size, void* d_ws, size_t ws_size,
                              hipStream_t stream) {
    const float* emb_user = (const float*)d_in[0];
    const float* emb_item = (const float*)d_in[1];
    const int* edge_rates = (const int*)d_in[2];
    const int* edge_rev   = (const int*)d_in[3];
    const int* eli        = (const int*)d_in[4];
    const float* b1_rates = (const float*)d_in[13];
    const float* b1_rev   = (const float*)d_in[14];
    const float* b2_rates = (const float*)d_in[15];
    const float* b2_rev   = (const float*)d_in[16];

    // workspace layout — total ~142 MiB
    char* p = (char*)d_ws;
    auto alloc = [&](size_t bytes) -> void* {
        void* q = (void*)p;
        p += (bytes + 511) & ~(size_t)511;
        return q;
    };
    int* deg_rates    = (int*)alloc((size_t)NUM_I * 4);              // 0.4 MB
    int* bucket_rates = (int*)alloc((size_t)NUM_I * CAP * 4);        // 19.2 MB
    int* deg_rev      = (int*)alloc((size_t)NUM_U * 4);              // 0.4 MB
    int* bucket_rev   = (int*)alloc((size_t)NUM_U * CAP * 4);        // 19.2 MB
    unsigned* meanI = (unsigned*)alloc((size_t)NUM_I * 64 * 4);      // 25.6 MB
    unsigned* meanU = (unsigned*)alloc((size_t)NUM_U * 64 * 4);      // 25.6 MB
    unsigned* xi    = (unsigned*)alloc((size_t)NUM_I * 64 * 4);      // 25.6 MB (embI->xi1->xi2)
    unsigned* xu    = (unsigned*)alloc((size_t)NUM_U * 64 * 4);      // 25.6 MB (embU->xu1->xu2)
    short* Bt = (short*)alloc((size_t)4 * 32768 * 2);                // 0.26 MB

    const int zeroBlocks = (NUM_I + 255) / 256;
    const int scatBlocks = (NE + 255) / 256;
    const int aggBlocks  = (NUM_I * 64 + 255) / 256;
    const int gemmBlocks = (NUM_I + 127) / 128;
    const int convBlocks = (NUM_I * 64 + 255) / 256;

    if (out_size > NL) {
        int tail = out_size - NL;
        zero_f32_kernel<<<(tail + 255) / 256, 256, 0, stream>>>((float*)d_out + NL, tail);
    }

    // ---- one-time prep: weight transpose, emb->bf16, buckets (reused by both layers)
    transpose_w4_kernel<<<512, 256, 0, stream>>>(
        (const float*)d_in[5], (const float*)d_in[6],
        (const float*)d_in[7], (const float*)d_in[8],
        (const float*)d_in[9], (const float*)d_in[10],
        (const float*)d_in[11], (const float*)d_in[12], Bt);

    conv_bf16_kernel<<<convBlocks, 256, 0, stream>>>(emb_user, xu, NUM_U * 64);
    conv_bf16_kernel<<<convBlocks, 256, 0, stream>>>(emb_item, xi, NUM_I * 64);

    zero_kernel<<<zeroBlocks, 256, 0, stream>>>(deg_rates, NUM_I);
    scatter_kernel<<<scatBlocks, 256, 0, stream>>>(edge_rates, deg_rates, bucket_rates, NE);
    zero_kernel<<<zeroBlocks, 256, 0, stream>>>(deg_rev, NUM_U);
    scatter_kernel<<<scatBlocks, 256, 0, stream>>>(edge_rev, deg_rev, bucket_rev, NE);

    // ---- layer 1: both aggs read pristine bf16 embs, then in-place GEMMs
    agg_kernel<<<aggBlocks, 256, 0, stream>>>(deg_rates, bucket_rates, xu, meanI, NUM_I);
    agg_kernel<<<aggBlocks, 256, 0, stream>>>(deg_rev, bucket_rev, xi, meanU, NUM_U);
    sage_fused_kernel<<<gemmBlocks, 256, 0, stream>>>(meanI, xi, Bt + 0 * 32768, b1_rates,
                                                      xi, NUM_I);
    sage_fused_kernel<<<gemmBlocks, 256, 0, stream>>>(meanU, xu, Bt + 1 * 32768, b1_rev,
                                                      xu, NUM_U);

    // ---- layer 2: both aggs read x1, then in-place GEMMs
    agg_kernel<<<aggBlocks, 256, 0, stream>>>(deg_rates, bucket_rates, xu, meanI, NUM_I);
    agg_kernel<<<aggBlocks, 256, 0, stream>>>(deg_rev, bucket_rev, xi, meanU, NUM_U);
    sage_fused_kernel<<<gemmBlocks, 256, 0, stream>>>(meanI, xi, Bt + 2 * 32768, b2_rates,
                                                      xi, NUM_I);
    sage_fused_kernel<<<gemmBlocks, 256, 0, stream>>>(meanU, xu, Bt + 3 * 32768, b2_rev,
                                                      xu, NUM_U);

    classifier_kernel<<<(NL * 64 + 255) / 256, 256, 0, stream>>>(xu, xi, eli,
                                                                 (float*)d_out, NL);
}

// Round 6
// 665.984 us; speedup vs baseline: 1.7287x; 1.2406x over previous
//
#include <hip/hip_runtime.h>
#include <hip/hip_bf16.h>

#define NUM_U 100000
#define NUM_I 100000
#define NE    1600000
#define NL    100000
#define CAP   48
#define NBIN  391        // ceil(100000/256) coarse bins (dst>>8)
#define BINCAP 4608      // per-bin capacity; E[bin]=4096, +8 sigma
#define ROUND  4096      // edges per partition block

typedef __attribute__((ext_vector_type(4))) float floatx4;
typedef __attribute__((ext_vector_type(8))) short shortx8;
typedef unsigned long long u64;

__device__ __forceinline__ float bf_lo(unsigned v) { return __uint_as_float(v << 16); }
__device__ __forceinline__ float bf_hi(unsigned v) { return __uint_as_float(v & 0xffff0000u); }

__device__ __forceinline__ unsigned pack_bf16x2(float lo, float hi) {
    __hip_bfloat16 l = __float2bfloat16(lo);
    __hip_bfloat16 h = __float2bfloat16(hi);
    unsigned short ul = *(unsigned short*)&l;
    unsigned short uh = *(unsigned short*)&h;
    return (unsigned)ul | ((unsigned)uh << 16);
}

__device__ __forceinline__ int clampi(int x, int hi) {
    return min(max(x, 0), hi - 1);
}

// -------- zero an int array
__global__ void zero_kernel(int* __restrict__ p, int n) {
    int i = blockIdx.x * blockDim.x + threadIdx.x;
    if (i < n) p[i] = 0;
}

// -------- zero f32 tail of d_out beyond NL (poisoned 0xAA otherwise)
__global__ void zero_f32_kernel(float* __restrict__ p, int n) {
    int i = blockIdx.x * blockDim.x + threadIdx.x;
    if (i < n) p[i] = 0.0f;
}

// -------- convert f32 [N][128] -> packed bf16x2 [N][64], coalesced streaming
__global__ void conv_bf16_kernel(const float* __restrict__ in, unsigned* __restrict__ out,
                                 int n_pairs) {
    int i = blockIdx.x * blockDim.x + threadIdx.x;
    if (i >= n_pairs) return;
    float2 v = ((const float2*)in)[i];
    out[i] = pack_bf16x2(v.x, v.y);
}

// -------- phase P: partition edges into coarse bins (dst>>8) with block-local
// counting sort so global writes are coalesced runs. bin_data entry = dst<<32|src.
__global__ __launch_bounds__(256) void partition_kernel(
    const int* __restrict__ edges, u64* __restrict__ bin_data,
    int* __restrict__ bin_cursor, int nE) {
    __shared__ int hist[NBIN];
    __shared__ int prefix[NBIN];
    __shared__ int gbase[NBIN];
    __shared__ __align__(16) u64 sorted[ROUND];

    const int tid  = threadIdx.x;
    const int lane = tid & 63;
    const int wv   = tid >> 6;
    const int base = blockIdx.x * ROUND;

    for (int k = tid; k < NBIN; k += 256) hist[k] = 0;
    __syncthreads();

    int mybin[16], myrank[16], mysrc[16], mydst[16];
#pragma unroll
    for (int r = 0; r < 16; r++) {
        int i = base + r * 256 + tid;
        mybin[r] = -1;
        if (i < nE) {
            mysrc[r] = clampi(edges[i], NUM_U);
            mydst[r] = clampi(edges[i + nE], NUM_I);
            mybin[r] = mydst[r] >> 8;
            myrank[r] = atomicAdd(&hist[mybin[r]], 1);
        }
    }
    __syncthreads();

    // exclusive scan of hist -> prefix (wave 0, shfl chunks of 64 with carry)
    if (wv == 0) {
        int carry = 0;
        for (int c = 0; c < NBIN; c += 64) {
            int idx = c + lane;
            int h = (idx < NBIN) ? hist[idx] : 0;
            int v = h;
            for (int o = 1; o < 64; o <<= 1) {
                int t = __shfl_up(v, o);
                if (lane >= o) v += t;
            }
            if (idx < NBIN) prefix[idx] = v - h + carry;
            carry += __shfl(v, 63);
        }
    }
    __syncthreads();

    // reorder into LDS (bin-major)
#pragma unroll
    for (int r = 0; r < 16; r++) {
        if (mybin[r] >= 0) {
            int j = prefix[mybin[r]] + myrank[r];
            sorted[j] = ((u64)(unsigned)mydst[r] << 32) | (unsigned)mysrc[r];
        }
    }
    __syncthreads();

    // reserve global space per bin (one atomic per bin per block)
    for (int b = tid; b < NBIN; b += 256) {
        int cnt = hist[b];
        gbase[b] = (cnt > 0) ? atomicAdd(&bin_cursor[b], cnt) : 0;
    }
    __syncthreads();

    // flush: consecutive j in a bin -> consecutive global addresses (coalesced runs)
    int total = min(ROUND, nE - base);
    for (int j = tid; j < total; j += 256) {
        u64 e = sorted[j];
        int b = (int)(e >> 40);              // dst>>8
        int pos = gbase[b] + (j - prefix[b]);
        if (pos < BINCAP)
            bin_data[(size_t)b * BINCAP + pos] = e;
    }
}

// -------- phase Q: one block per bin; build 256-dst bucket rows in LDS, then
// stream deg + bucket out fully coalesced.
__global__ __launch_bounds__(256) void binscatter_kernel(
    const u64* __restrict__ bin_data, const int* __restrict__ bin_cursor,
    int* __restrict__ deg, int* __restrict__ bucket, int n_dst) {
    __shared__ int lbucket[256 * CAP];   // 48 KB
    __shared__ int ldeg[256];
    const int tid = threadIdx.x;
    const int b = blockIdx.x;
    const int dstbase = b << 8;

    ldeg[tid] = 0;
    __syncthreads();

    int count = min(bin_cursor[b], BINCAP);
    for (int j = tid; j < count; j += 256) {
        u64 e = bin_data[(size_t)b * BINCAP + j];
        int src = (int)(unsigned)e;
        int dl = ((int)(e >> 32)) & 255;
        int pos = atomicAdd(&ldeg[dl], 1);
        if (pos < CAP) lbucket[dl * CAP + pos] = src;
    }
    __syncthreads();

    if (dstbase + tid < n_dst) deg[dstbase + tid] = ldeg[tid];
    int limit = min(256, n_dst - dstbase) * CAP;
    for (int k = tid; k < limit; k += 256)
        bucket[(size_t)dstbase * CAP + k] = lbucket[k];
}

// -------- per-dst mean aggregation: one wave per dst node, 2 features/lane.
__global__ __launch_bounds__(256) void agg_kernel(
    const int* __restrict__ deg, const int* __restrict__ bucket,
    const unsigned* __restrict__ xb, unsigned* __restrict__ mean_out, int n_dst) {
    int wave = (blockIdx.x * blockDim.x + threadIdx.x) >> 6;
    int lane = threadIdx.x & 63;
    if (wave >= n_dst) return;
    int d = deg[wave];
    int cnt = min(d, CAP);
    int srcs = (lane < cnt) ? bucket[wave * CAP + lane] : 0;
    float a0 = 0.f, a1 = 0.f;
    int e = 0;
    for (; e + 4 <= cnt; e += 4) {
        int s0 = __shfl(srcs, e);
        int s1 = __shfl(srcs, e + 1);
        int s2 = __shfl(srcs, e + 2);
        int s3 = __shfl(srcs, e + 3);
        unsigned v0 = xb[(size_t)s0 * 64 + lane];
        unsigned v1 = xb[(size_t)s1 * 64 + lane];
        unsigned v2 = xb[(size_t)s2 * 64 + lane];
        unsigned v3 = xb[(size_t)s3 * 64 + lane];
        a0 += bf_lo(v0) + bf_lo(v1) + bf_lo(v2) + bf_lo(v3);
        a1 += bf_hi(v0) + bf_hi(v1) + bf_hi(v2) + bf_hi(v3);
    }
    for (; e < cnt; e++) {
        int s0 = __shfl(srcs, e);
        unsigned v0 = xb[(size_t)s0 * 64 + lane];
        a0 += bf_lo(v0); a1 += bf_hi(v0);
    }
    float scale = 1.0f / (float)max(d, 1);
    mean_out[(size_t)wave * 64 + lane] = pack_bf16x2(a0 * scale, a1 * scale);
}

// -------- transpose the 4 f32 weight pairs into bf16 Bt[which][n][k], k=[w_l rows|w_r rows]
__global__ void transpose_w4_kernel(
    const float* __restrict__ w1l_rates, const float* __restrict__ w1r_rates,
    const float* __restrict__ w1l_rev,   const float* __restrict__ w1r_rev,
    const float* __restrict__ w2l_rates, const float* __restrict__ w2r_rates,
    const float* __restrict__ w2l_rev,   const float* __restrict__ w2r_rev,
    short* __restrict__ Bt) {
    int idx = blockIdx.x * blockDim.x + threadIdx.x;  // 0 .. 4*32768-1
    int which = idx >> 15;
    int r = idx & 32767;
    int n = r >> 8;
    int k = r & 255;
    const float *wl, *wr;
    switch (which) {
        case 0:  wl = w1l_rates; wr = w1r_rates; break;
        case 1:  wl = w1l_rev;   wr = w1r_rev;   break;
        case 2:  wl = w2l_rates; wr = w2r_rates; break;
        default: wl = w2l_rev;   wr = w2r_rev;   break;
    }
    float v = (k < 128) ? wl[k * 128 + n] : wr[(k - 128) * 128 + n];
    __hip_bfloat16 b = __float2bfloat16(v);
    Bt[idx] = *(const short*)&b;
}

// -------- fused: out = relu(normalize(mean @ w_l + b + x_dst @ w_r)), bf16 out
__global__ __launch_bounds__(256) void sage_fused_kernel(
    const unsigned* __restrict__ meanb,   // [N][64] packed bf16x2
    const unsigned* __restrict__ xdstb,   // [N][64] packed bf16x2
    const short* __restrict__ Bt,         // [128][256] bf16 bits, Bt[n][k]
    const float* __restrict__ bias,       // [128] f32
    unsigned* __restrict__ outb,          // [N][64] packed bf16x2 (may alias xdstb)
    int n_rows) {
    __shared__ __align__(16) short A_lds[128 * 72];
    __shared__ float rowsum[128][2];

    const int tid  = threadIdx.x;
    const int lane = tid & 63;
    const int wv   = tid >> 6;
    const int wm   = wv >> 1;
    const int wn   = wv & 1;
    const int rb   = blockIdx.x * 128;
    const int l15  = lane & 15;
    const int lq   = lane >> 4;

    floatx4 acc[4][4];
#pragma unroll
    for (int nt = 0; nt < 4; nt++) {
        float b = bias[wn * 64 + nt * 16 + l15];
#pragma unroll
        for (int mt = 0; mt < 4; mt++) acc[mt][nt] = (floatx4){b, b, b, b};
    }

    for (int kt = 0; kt < 4; kt++) {
        __syncthreads();
        const unsigned* srcbuf = (kt < 2) ? meanb : xdstb;
        const int kbase_u = (kt & 1) * 32;
#pragma unroll
        for (int j = 0; j < 4; j++) {
            int c = tid + j * 256;
            int row = c >> 3;
            int kc = (c & 7) * 8;
            int grow = rb + row;
            uint4 v = make_uint4(0u, 0u, 0u, 0u);
            if (grow < n_rows)
                v = *(const uint4*)(srcbuf + (size_t)grow * 64 + kbase_u + (kc >> 1));
            *(uint4*)&A_lds[row * 72 + kc] = v;
        }
        __syncthreads();

#pragma unroll
        for (int kk = 0; kk < 64; kk += 32) {
            shortx8 af[4], bfr[4];
#pragma unroll
            for (int mt = 0; mt < 4; mt++) {
                int row_l = wm * 64 + mt * 16 + l15;
                af[mt] = *(const shortx8*)&A_lds[row_l * 72 + kk + lq * 8];
            }
#pragma unroll
            for (int nt = 0; nt < 4; nt++) {
                int col = wn * 64 + nt * 16 + l15;
                int kg = kt * 64 + kk + lq * 8;
                bfr[nt] = *(const shortx8*)(Bt + col * 256 + kg);
            }
#pragma unroll
            for (int mt = 0; mt < 4; mt++)
#pragma unroll
                for (int nt = 0; nt < 4; nt++)
                    acc[mt][nt] = __builtin_amdgcn_mfma_f32_16x16x32_bf16(
                        af[mt], bfr[nt], acc[mt][nt], 0, 0, 0);
        }
    }

#pragma unroll
    for (int mt = 0; mt < 4; mt++) {
#pragma unroll
        for (int r = 0; r < 4; r++) {
            float p = 0.f;
#pragma unroll
            for (int nt = 0; nt < 4; nt++) { float x = acc[mt][nt][r]; p += x * x; }
            for (int o = 1; o < 16; o <<= 1) p += __shfl_xor(p, o);
            if (l15 == 0) rowsum[wm * 64 + mt * 16 + lq * 4 + r][wn] = p;
        }
    }
    __syncthreads();

#pragma unroll
    for (int mt = 0; mt < 4; mt++) {
#pragma unroll
        for (int r = 0; r < 4; r++) {
            int row_l = wm * 64 + mt * 16 + lq * 4 + r;
            int grow = rb + row_l;
            float s = rowsum[row_l][0] + rowsum[row_l][1];
            float inv = 1.f / fmaxf(sqrtf(s), 1e-12f);
#pragma unroll
            for (int nt = 0; nt < 4; nt++) {
                float v = fmaxf(acc[mt][nt][r] * inv, 0.f);
                float vnb = __shfl_xor(v, 1);
                if (grow < n_rows && (l15 & 1) == 0) {
                    int colpair = (wn * 64 + nt * 16 + l15) >> 1;
                    outb[(size_t)grow * 64 + colpair] = pack_bf16x2(v, vnb);
                }
            }
        }
    }
}

// -------- classifier: dot(xu2[src], xi2[dst]) per labeled edge, one wave per pair
__global__ __launch_bounds__(256) void classifier_kernel(
    const unsigned* __restrict__ xu, const unsigned* __restrict__ xi,
    const int* __restrict__ eli, float* __restrict__ out, int nL) {
    int wave = (blockIdx.x * blockDim.x + threadIdx.x) >> 6;
    int lane = threadIdx.x & 63;
    if (wave >= nL) return;
    int su = clampi(eli[wave], NUM_U);
    int di = clampi(eli[wave + nL], NUM_I);
    unsigned a = xu[(size_t)su * 64 + lane];
    unsigned b = xi[(size_t)di * 64 + lane];
    float p = bf_lo(a) * bf_lo(b) + bf_hi(a) * bf_hi(b);
    for (int o = 32; o; o >>= 1) p += __shfl_xor(p, o);
    if (lane == 0) out[wave] = p;
}

extern "C" void kernel_launch(void* const* d_in, const int* in_sizes, int n_in,
                              void* d_out, int out_size, void* d_ws, size_t ws_size,
                              hipStream_t stream) {
    const float* emb_user = (const float*)d_in[0];
    const float* emb_item = (const float*)d_in[1];
    const int* edge_rates = (const int*)d_in[2];
    const int* edge_rev   = (const int*)d_in[3];
    const int* eli        = (const int*)d_in[4];
    const float* b1_rates = (const float*)d_in[13];
    const float* b1_rev   = (const float*)d_in[14];
    const float* b2_rates = (const float*)d_in[15];
    const float* b2_rev   = (const float*)d_in[16];

    // workspace layout — total ~142 MiB (bin_data aliases meanI, dead before aggs)
    char* p = (char*)d_ws;
    auto alloc = [&](size_t bytes) -> void* {
        void* q = (void*)p;
        p += (bytes + 511) & ~(size_t)511;
        return q;
    };
    int* deg_rates    = (int*)alloc((size_t)NUM_I * 4);
    int* bucket_rates = (int*)alloc((size_t)NUM_I * CAP * 4);
    int* deg_rev      = (int*)alloc((size_t)NUM_U * 4);
    int* bucket_rev   = (int*)alloc((size_t)NUM_U * CAP * 4);
    unsigned* meanI = (unsigned*)alloc((size_t)NUM_I * 64 * 4);
    unsigned* meanU = (unsigned*)alloc((size_t)NUM_U * 64 * 4);
    unsigned* xi    = (unsigned*)alloc((size_t)NUM_I * 64 * 4);   // embI->xi1->xi2
    unsigned* xu    = (unsigned*)alloc((size_t)NUM_U * 64 * 4);   // embU->xu1->xu2
    short* Bt = (short*)alloc((size_t)4 * 32768 * 2);
    int* bin_cursor = (int*)alloc((size_t)NBIN * 4);
    u64* bin_data = (u64*)meanI;   // 391*4608*8 = 14.4 MB <= 25.6 MB, dead before aggs

    const int partBlocks = (NE + ROUND - 1) / ROUND;   // 391
    const int aggBlocks  = (NUM_I * 64 + 255) / 256;
    const int gemmBlocks = (NUM_I + 127) / 128;
    const int convBlocks = (NUM_I * 64 + 255) / 256;

    if (out_size > NL) {
        int tail = out_size - NL;
        zero_f32_kernel<<<(tail + 255) / 256, 256, 0, stream>>>((float*)d_out + NL, tail);
    }

    // ---- one-time prep
    transpose_w4_kernel<<<512, 256, 0, stream>>>(
        (const float*)d_in[5], (const float*)d_in[6],
        (const float*)d_in[7], (const float*)d_in[8],
        (const float*)d_in[9], (const float*)d_in[10],
        (const float*)d_in[11], (const float*)d_in[12], Bt);

    conv_bf16_kernel<<<convBlocks, 256, 0, stream>>>(emb_user, xu, NUM_U * 64);
    conv_bf16_kernel<<<convBlocks, 256, 0, stream>>>(emb_item, xi, NUM_I * 64);

    // buckets: two-phase coalesced scatter, once per edge type (reused by both layers)
    zero_kernel<<<2, 256, 0, stream>>>(bin_cursor, NBIN);
    partition_kernel<<<partBlocks, 256, 0, stream>>>(edge_rates, bin_data, bin_cursor, NE);
    binscatter_kernel<<<NBIN, 256, 0, stream>>>(bin_data, bin_cursor,
                                                deg_rates, bucket_rates, NUM_I);
    zero_kernel<<<2, 256, 0, stream>>>(bin_cursor, NBIN);
    partition_kernel<<<partBlocks, 256, 0, stream>>>(edge_rev, bin_data, bin_cursor, NE);
    binscatter_kernel<<<NBIN, 256, 0, stream>>>(bin_data, bin_cursor,
                                                deg_rev, bucket_rev, NUM_U);

    // ---- layer 1 (aggs read pristine bf16 embs; in-place GEMMs)
    agg_kernel<<<aggBlocks, 256, 0, stream>>>(deg_rates, bucket_rates, xu, meanI, NUM_I);
    agg_kernel<<<aggBlocks, 256, 0, stream>>>(deg_rev, bucket_rev, xi, meanU, NUM_U);
    sage_fused_kernel<<<gemmBlocks, 256, 0, stream>>>(meanI, xi, Bt + 0 * 32768, b1_rates,
                                                      xi, NUM_I);
    sage_fused_kernel<<<gemmBlocks, 256, 0, stream>>>(meanU, xu, Bt + 1 * 32768, b1_rev,
                                                      xu, NUM_U);

    // ---- layer 2
    agg_kernel<<<aggBlocks, 256, 0, stream>>>(deg_rates, bucket_rates, xu, meanI, NUM_I);
    agg_kernel<<<aggBlocks, 256, 0, stream>>>(deg_rev, bucket_rev, xi, meanU, NUM_U);
    sage_fused_kernel<<<gemmBlocks, 256, 0, stream>>>(meanI, xi, Bt + 2 * 32768, b2_rates,
                                                      xi, NUM_I);
    sage_fused_kernel<<<gemmBlocks, 256, 0, stream>>>(meanU, xu, Bt + 3 * 32768, b2_rev,
                                                      xu, NUM_U);

    classifier_kernel<<<(NL * 64 + 255) / 256, 256, 0, stream>>>(xu, xi, eli,
                                                                 (float*)d_out, NL);
}

// Round 7
// 637.355 us; speedup vs baseline: 1.8064x; 1.0449x over previous
//
#include <hip/hip_runtime.h>
#include <hip/hip_bf16.h>

#define NUM_U 100000
#define NUM_I 100000
#define NE    1600000
#define NL    100000
#define CAP   48
#define NBIN  391        // ceil(100000/256) coarse bins (dst>>8)
#define BINCAP 4608      // per-bin capacity; E[bin]=4096, +8 sigma
#define ROUND  4096      // edges per partition block
#define PB    391        // partition blocks per edge type = ceil(NE/ROUND)

typedef __attribute__((ext_vector_type(4))) float floatx4;
typedef __attribute__((ext_vector_type(8))) short shortx8;
typedef unsigned long long u64;

__device__ __forceinline__ float bf_lo(unsigned v) { return __uint_as_float(v << 16); }
__device__ __forceinline__ float bf_hi(unsigned v) { return __uint_as_float(v & 0xffff0000u); }

__device__ __forceinline__ unsigned pack_bf16x2(float lo, float hi) {
    __hip_bfloat16 l = __float2bfloat16(lo);
    __hip_bfloat16 h = __float2bfloat16(hi);
    unsigned short ul = *(unsigned short*)&l;
    unsigned short uh = *(unsigned short*)&h;
    return (unsigned)ul | ((unsigned)uh << 16);
}

__device__ __forceinline__ int clampi(int x, int hi) {
    return min(max(x, 0), hi - 1);
}

// -------- zero f32 tail of d_out beyond NL (poisoned 0xAA otherwise)
__global__ void zero_f32_kernel(float* __restrict__ p, int n) {
    int i = blockIdx.x * blockDim.x + threadIdx.x;
    if (i < n) p[i] = 0.0f;
}

// -------- both emb tables f32 [N][128] -> packed bf16x2, one dispatch
__global__ void conv2_kernel(const float* __restrict__ emb_u, const float* __restrict__ emb_i,
                             unsigned* __restrict__ xu, unsigned* __restrict__ xi) {
    int i = blockIdx.x * blockDim.x + threadIdx.x;
    const int nu = NUM_U * 64;
    if (i < nu) {
        float2 v = ((const float2*)emb_u)[i];
        xu[i] = pack_bf16x2(v.x, v.y);
    } else if (i < nu + NUM_I * 64) {
        int j = i - nu;
        float2 v = ((const float2*)emb_i)[j];
        xi[j] = pack_bf16x2(v.x, v.y);
    }
}

// -------- transpose the 4 f32 weight pairs into bf16 Bt[which][n][k]; also zeros bin_cursor
__global__ void transpose_w4_kernel(
    const float* __restrict__ w1l_rates, const float* __restrict__ w1r_rates,
    const float* __restrict__ w1l_rev,   const float* __restrict__ w1r_rev,
    const float* __restrict__ w2l_rates, const float* __restrict__ w2r_rates,
    const float* __restrict__ w2l_rev,   const float* __restrict__ w2r_rev,
    short* __restrict__ Bt, int* __restrict__ bin_cursor) {
    int idx = blockIdx.x * blockDim.x + threadIdx.x;  // 0 .. 4*32768-1
    if (idx < 2 * NBIN) bin_cursor[idx] = 0;
    int which = idx >> 15;
    int r = idx & 32767;
    int n = r >> 8;
    int k = r & 255;
    const float *wl, *wr;
    switch (which) {
        case 0:  wl = w1l_rates; wr = w1r_rates; break;
        case 1:  wl = w1l_rev;   wr = w1r_rev;   break;
        case 2:  wl = w2l_rates; wr = w2r_rates; break;
        default: wl = w2l_rev;   wr = w2r_rev;   break;
    }
    float v = (k < 128) ? wl[k * 128 + n] : wr[(k - 128) * 128 + n];
    __hip_bfloat16 b = __float2bfloat16(v);
    Bt[idx] = *(const short*)&b;
}

// -------- phase P (both edge types): block-local counting sort by dst>>8, coalesced
// runs into per-bin regions. bin_data entry = dst<<32|src.
__global__ __launch_bounds__(256) void partition2_kernel(
    const int* __restrict__ edges0, const int* __restrict__ edges1,
    u64* __restrict__ bd0, u64* __restrict__ bd1, int* __restrict__ cur) {
    __shared__ int hist[NBIN];
    __shared__ int prefix[NBIN];
    __shared__ int gbase[NBIN];
    __shared__ __align__(16) u64 sorted[ROUND];

    const int type = (blockIdx.x >= PB) ? 1 : 0;
    const int* edges = type ? edges1 : edges0;
    u64* bin_data = type ? bd1 : bd0;
    int* bin_cursor = cur + type * NBIN;
    const int blk  = blockIdx.x - type * PB;
    const int tid  = threadIdx.x;
    const int lane = tid & 63;
    const int wv   = tid >> 6;
    const int base = blk * ROUND;

    for (int k = tid; k < NBIN; k += 256) hist[k] = 0;
    __syncthreads();

    int mybin[16], myrank[16], mysrc[16], mydst[16];
#pragma unroll
    for (int r = 0; r < 16; r++) {
        int i = base + r * 256 + tid;
        mybin[r] = -1;
        if (i < NE) {
            mysrc[r] = clampi(edges[i], NUM_U);
            mydst[r] = clampi(edges[i + NE], NUM_I);
            mybin[r] = mydst[r] >> 8;
            myrank[r] = atomicAdd(&hist[mybin[r]], 1);
        }
    }
    __syncthreads();

    if (wv == 0) {   // exclusive scan of hist -> prefix
        int carry = 0;
        for (int c = 0; c < NBIN; c += 64) {
            int idx = c + lane;
            int h = (idx < NBIN) ? hist[idx] : 0;
            int v = h;
            for (int o = 1; o < 64; o <<= 1) {
                int t = __shfl_up(v, o);
                if (lane >= o) v += t;
            }
            if (idx < NBIN) prefix[idx] = v - h + carry;
            carry += __shfl(v, 63);
        }
    }
    __syncthreads();

#pragma unroll
    for (int r = 0; r < 16; r++) {
        if (mybin[r] >= 0) {
            int j = prefix[mybin[r]] + myrank[r];
            sorted[j] = ((u64)(unsigned)mydst[r] << 32) | (unsigned)mysrc[r];
        }
    }
    __syncthreads();

    for (int b = tid; b < NBIN; b += 256) {
        int cnt = hist[b];
        gbase[b] = (cnt > 0) ? atomicAdd(&bin_cursor[b], cnt) : 0;
    }
    __syncthreads();

    int total = min(ROUND, NE - base);
    for (int j = tid; j < total; j += 256) {
        u64 e = sorted[j];
        int b = (int)(e >> 40);
        int pos = gbase[b] + (j - prefix[b]);
        if (pos < BINCAP)
            bin_data[(size_t)b * BINCAP + pos] = e;
    }
}

// -------- phase Q (both edge types): one block per bin; LDS bucket build, coalesced out
__global__ __launch_bounds__(256) void binscatter2_kernel(
    const u64* __restrict__ bd0, const u64* __restrict__ bd1, const int* __restrict__ cur,
    int* __restrict__ deg0, int* __restrict__ bucket0,
    int* __restrict__ deg1, int* __restrict__ bucket1) {
    __shared__ int lbucket[256 * CAP];   // 48 KB
    __shared__ int ldeg[256];
    const int type = (blockIdx.x >= NBIN) ? 1 : 0;
    const int b = blockIdx.x - type * NBIN;
    const u64* bin_data = type ? bd1 : bd0;
    int* deg = type ? deg1 : deg0;
    int* bucket = type ? bucket1 : bucket0;
    const int tid = threadIdx.x;
    const int dstbase = b << 8;
    const int n_dst = NUM_I;

    ldeg[tid] = 0;
    __syncthreads();

    int count = min(cur[type * NBIN + b], BINCAP);
    for (int j = tid; j < count; j += 256) {
        u64 e = bin_data[(size_t)b * BINCAP + j];
        int src = (int)(unsigned)e;
        int dl = ((int)(e >> 32)) & 255;
        int pos = atomicAdd(&ldeg[dl], 1);
        if (pos < CAP) lbucket[dl * CAP + pos] = src;
    }
    __syncthreads();

    if (dstbase + tid < n_dst) deg[dstbase + tid] = ldeg[tid];
    int limit = min(256, n_dst - dstbase) * CAP;
    for (int k = tid; k < limit; k += 256)
        bucket[(size_t)dstbase * CAP + k] = lbucket[k];
}

// -------- merged aggregation (both edge types): one wave per dst node.
// mean stores are non-temporal to keep the gather tables L3-resident.
__global__ __launch_bounds__(256) void agg2_kernel(
    const int* __restrict__ degA, const int* __restrict__ bucketA,
    const unsigned* __restrict__ xA, unsigned* __restrict__ outA,
    const int* __restrict__ degB, const int* __restrict__ bucketB,
    const unsigned* __restrict__ xB, unsigned* __restrict__ outB) {
    int w = (blockIdx.x * blockDim.x + threadIdx.x) >> 6;
    int lane = threadIdx.x & 63;
    const int* deg; const int* bucket; const unsigned* xb; unsigned* mo; int node;
    if (w < NUM_I) { deg = degA; bucket = bucketA; xb = xA; mo = outA; node = w; }
    else if (w < NUM_I + NUM_U) { deg = degB; bucket = bucketB; xb = xB; mo = outB; node = w - NUM_I; }
    else return;

    int d = deg[node];
    int cnt = min(d, CAP);
    int srcs = (lane < cnt) ? bucket[node * CAP + lane] : 0;
    float a0 = 0.f, a1 = 0.f;
    int e = 0;
    for (; e + 4 <= cnt; e += 4) {
        int s0 = __shfl(srcs, e);
        int s1 = __shfl(srcs, e + 1);
        int s2 = __shfl(srcs, e + 2);
        int s3 = __shfl(srcs, e + 3);
        unsigned v0 = xb[(size_t)s0 * 64 + lane];
        unsigned v1 = xb[(size_t)s1 * 64 + lane];
        unsigned v2 = xb[(size_t)s2 * 64 + lane];
        unsigned v3 = xb[(size_t)s3 * 64 + lane];
        a0 += bf_lo(v0) + bf_lo(v1) + bf_lo(v2) + bf_lo(v3);
        a1 += bf_hi(v0) + bf_hi(v1) + bf_hi(v2) + bf_hi(v3);
    }
    for (; e < cnt; e++) {
        int s0 = __shfl(srcs, e);
        unsigned v0 = xb[(size_t)s0 * 64 + lane];
        a0 += bf_lo(v0); a1 += bf_hi(v0);
    }
    float scale = 1.0f / (float)max(d, 1);
    __builtin_nontemporal_store(pack_bf16x2(a0 * scale, a1 * scale),
                                &mo[(size_t)node * 64 + lane]);
}

// -------- merged fused GEMM (both node types): out = relu(normalize(mean@wl + b + x@wr))
__global__ __launch_bounds__(256) void gemm2_kernel(
    const unsigned* __restrict__ meanA, unsigned* __restrict__ xA,
    const short* __restrict__ BtA, const float* __restrict__ biasA,
    const unsigned* __restrict__ meanB, unsigned* __restrict__ xB,
    const short* __restrict__ BtB, const float* __restrict__ biasB,
    int nblocksA) {
    __shared__ __align__(16) short A_lds[128 * 72];
    __shared__ float rowsum[128][2];

    const int half = (blockIdx.x >= nblocksA) ? 1 : 0;
    const unsigned* meanb = half ? meanB : meanA;
    const unsigned* xdstb = half ? xB : xA;
    unsigned* outb = half ? xB : xA;
    const short* Bt = half ? BtB : BtA;
    const float* bias = half ? biasB : biasA;
    const int rb = (blockIdx.x - half * nblocksA) * 128;
    const int n_rows = NUM_I;

    const int tid  = threadIdx.x;
    const int lane = tid & 63;
    const int wv   = tid >> 6;
    const int wm   = wv >> 1;
    const int wn   = wv & 1;
    const int l15  = lane & 15;
    const int lq   = lane >> 4;

    floatx4 acc[4][4];
#pragma unroll
    for (int nt = 0; nt < 4; nt++) {
        float b = bias[wn * 64 + nt * 16 + l15];
#pragma unroll
        for (int mt = 0; mt < 4; mt++) acc[mt][nt] = (floatx4){b, b, b, b};
    }

    for (int kt = 0; kt < 4; kt++) {
        __syncthreads();
        const unsigned* srcbuf = (kt < 2) ? meanb : xdstb;
        const int kbase_u = (kt & 1) * 32;
#pragma unroll
        for (int j = 0; j < 4; j++) {
            int c = tid + j * 256;
            int row = c >> 3;
            int kc = (c & 7) * 8;
            int grow = rb + row;
            uint4 v = make_uint4(0u, 0u, 0u, 0u);
            if (grow < n_rows)
                v = *(const uint4*)(srcbuf + (size_t)grow * 64 + kbase_u + (kc >> 1));
            *(uint4*)&A_lds[row * 72 + kc] = v;
        }
        __syncthreads();

#pragma unroll
        for (int kk = 0; kk < 64; kk += 32) {
            shortx8 af[4], bfr[4];
#pragma unroll
            for (int mt = 0; mt < 4; mt++) {
                int row_l = wm * 64 + mt * 16 + l15;
                af[mt] = *(const shortx8*)&A_lds[row_l * 72 + kk + lq * 8];
            }
#pragma unroll
            for (int nt = 0; nt < 4; nt++) {
                int col = wn * 64 + nt * 16 + l15;
                int kg = kt * 64 + kk + lq * 8;
                bfr[nt] = *(const shortx8*)(Bt + col * 256 + kg);
            }
#pragma unroll
            for (int mt = 0; mt < 4; mt++)
#pragma unroll
                for (int nt = 0; nt < 4; nt++)
                    acc[mt][nt] = __builtin_amdgcn_mfma_f32_16x16x32_bf16(
                        af[mt], bfr[nt], acc[mt][nt], 0, 0, 0);
        }
    }

#pragma unroll
    for (int mt = 0; mt < 4; mt++) {
#pragma unroll
        for (int r = 0; r < 4; r++) {
            float p = 0.f;
#pragma unroll
            for (int nt = 0; nt < 4; nt++) { float x = acc[mt][nt][r]; p += x * x; }
            for (int o = 1; o < 16; o <<= 1) p += __shfl_xor(p, o);
            if (l15 == 0) rowsum[wm * 64 + mt * 16 + lq * 4 + r][wn] = p;
        }
    }
    __syncthreads();

#pragma unroll
    for (int mt = 0; mt < 4; mt++) {
#pragma unroll
        for (int r = 0; r < 4; r++) {
            int row_l = wm * 64 + mt * 16 + lq * 4 + r;
            int grow = rb + row_l;
            float s = rowsum[row_l][0] + rowsum[row_l][1];
            float inv = 1.f / fmaxf(sqrtf(s), 1e-12f);
#pragma unroll
            for (int nt = 0; nt < 4; nt++) {
                float v = fmaxf(acc[mt][nt][r] * inv, 0.f);
                float vnb = __shfl_xor(v, 1);
                if (grow < n_rows && (l15 & 1) == 0) {
                    int colpair = (wn * 64 + nt * 16 + l15) >> 1;
                    outb[(size_t)grow * 64 + colpair] = pack_bf16x2(v, vnb);
                }
            }
        }
    }
}

// -------- classifier: dot(xu2[src], xi2[dst]) per labeled edge, one wave per pair
__global__ __launch_bounds__(256) void classifier_kernel(
    const unsigned* __restrict__ xu, const unsigned* __restrict__ xi,
    const int* __restrict__ eli, float* __restrict__ out, int nL) {
    int wave = (blockIdx.x * blockDim.x + threadIdx.x) >> 6;
    int lane = threadIdx.x & 63;
    if (wave >= nL) return;
    int su = clampi(eli[wave], NUM_U);
    int di = clampi(eli[wave + nL], NUM_I);
    unsigned a = xu[(size_t)su * 64 + lane];
    unsigned b = xi[(size_t)di * 64 + lane];
    float p = bf_lo(a) * bf_lo(b) + bf_hi(a) * bf_hi(b);
    for (int o = 32; o; o >>= 1) p += __shfl_xor(p, o);
    if (lane == 0) __builtin_nontemporal_store(p, &out[wave]);
}

extern "C" void kernel_launch(void* const* d_in, const int* in_sizes, int n_in,
                              void* d_out, int out_size, void* d_ws, size_t ws_size,
                              hipStream_t stream) {
    const float* emb_user = (const float*)d_in[0];
    const float* emb_item = (const float*)d_in[1];
    const int* edge_rates = (const int*)d_in[2];
    const int* edge_rev   = (const int*)d_in[3];
    const int* eli        = (const int*)d_in[4];
    const float* b1_rates = (const float*)d_in[13];
    const float* b1_rev   = (const float*)d_in[14];
    const float* b2_rates = (const float*)d_in[15];
    const float* b2_rev   = (const float*)d_in[16];

    // workspace layout — ~142 MiB (bin_data regions alias meanI/meanU, dead before aggs)
    char* p = (char*)d_ws;
    auto alloc = [&](size_t bytes) -> void* {
        void* q = (void*)p;
        p += (bytes + 511) & ~(size_t)511;
        return q;
    };
    int* deg_rates    = (int*)alloc((size_t)NUM_I * 4);
    int* bucket_rates = (int*)alloc((size_t)NUM_I * CAP * 4);
    int* deg_rev      = (int*)alloc((size_t)NUM_U * 4);
    int* bucket_rev   = (int*)alloc((size_t)NUM_U * CAP * 4);
    unsigned* meanI = (unsigned*)alloc((size_t)NUM_I * 64 * 4);
    unsigned* meanU = (unsigned*)alloc((size_t)NUM_U * 64 * 4);
    unsigned* xi    = (unsigned*)alloc((size_t)NUM_I * 64 * 4);   // embI->xi1->xi2
    unsigned* xu    = (unsigned*)alloc((size_t)NUM_U * 64 * 4);   // embU->xu1->xu2
    short* Bt = (short*)alloc((size_t)4 * 32768 * 2);
    int* bin_cursor = (int*)alloc((size_t)2 * NBIN * 4);
    u64* bd0 = (u64*)meanI;   // 391*4608*8 = 14.4 MB <= 25.6 MB
    u64* bd1 = (u64*)meanU;

    const int gemmBlocks = (NUM_I + 127) / 128;                 // 782
    const int agg2Blocks = ((NUM_I + NUM_U) * 64 + 255) / 256;  // 50000
    const int conv2Blocks = ((NUM_U + NUM_I) * 64 + 255) / 256;

    if (out_size > NL) {
        int tail = out_size - NL;
        zero_f32_kernel<<<(tail + 255) / 256, 256, 0, stream>>>((float*)d_out + NL, tail);
    }

    // ---- one-time prep (3 dispatches)
    transpose_w4_kernel<<<512, 256, 0, stream>>>(
        (const float*)d_in[5], (const float*)d_in[6],
        (const float*)d_in[7], (const float*)d_in[8],
        (const float*)d_in[9], (const float*)d_in[10],
        (const float*)d_in[11], (const float*)d_in[12], Bt, bin_cursor);
    conv2_kernel<<<conv2Blocks, 256, 0, stream>>>(emb_user, emb_item, xu, xi);
    partition2_kernel<<<2 * PB, 256, 0, stream>>>(edge_rates, edge_rev, bd0, bd1, bin_cursor);
    binscatter2_kernel<<<2 * NBIN, 256, 0, stream>>>(bd0, bd1, bin_cursor,
                                                     deg_rates, bucket_rates,
                                                     deg_rev, bucket_rev);

    // ---- layer 1 (aggs read pristine bf16 embs; in-place GEMMs)
    agg2_kernel<<<agg2Blocks, 256, 0, stream>>>(deg_rates, bucket_rates, xu, meanI,
                                                deg_rev, bucket_rev, xi, meanU);
    gemm2_kernel<<<2 * gemmBlocks, 256, 0, stream>>>(meanI, xi, Bt + 0 * 32768, b1_rates,
                                                     meanU, xu, Bt + 1 * 32768, b1_rev,
                                                     gemmBlocks);

    // ---- layer 2 (identical pointers: in-place buffers)
    agg2_kernel<<<agg2Blocks, 256, 0, stream>>>(deg_rates, bucket_rates, xu, meanI,
                                                deg_rev, bucket_rev, xi, meanU);
    gemm2_kernel<<<2 * gemmBlocks, 256, 0, stream>>>(meanI, xi, Bt + 2 * 32768, b2_rates,
                                                     meanU, xu, Bt + 3 * 32768, b2_rev,
                                                     gemmBlocks);

    classifier_kernel<<<(NL * 64 + 255) / 256, 256, 0, stream>>>(xu, xi, eli,
                                                                 (float*)d_out, NL);
}